// Round 16
// baseline (163.895 us; speedup 1.0000x reference)
//
#include <hip/hip_runtime.h>

#define NB 8192
#define NL 64
#define NH 128

typedef __bf16 bf16x8 __attribute__((ext_vector_type(8)));
typedef float f32x4 __attribute__((ext_vector_type(4)));
typedef float f32x2 __attribute__((ext_vector_type(2)));
typedef unsigned short ushort8 __attribute__((ext_vector_type(8)));

// phys->logical permutation for the h buffer (GEMM1 writeback pair-packing):
// phys p = w*32 + ci*2 + half  holds logical  w*32 + half*16 + ci
__device__ __host__ __forceinline__ int p2l(int p) {
  return (p & ~31) + ((p & 1) << 4) + ((p & 31) >> 1);
}
// phys->logical permutation for the x=concat(x1,x2) buffer (x1x2 pair-packing):
// phys even p -> x1 col p/2 ; phys odd p -> x2 col p/2 (logical 64+p/2)
__device__ __host__ __forceinline__ int pi2(int p) {
  return (p & 1) ? 64 + (p >> 1) : (p >> 1);
}

__device__ __forceinline__ unsigned pk2(float lo, float hi) {
  union { __bf16 b[2]; unsigned u; } t;
  t.b[0] = (__bf16)lo; t.b[1] = (__bf16)hi;
  return t.u;
}

// ---------------------------------------------------------------------------
// Repack weights (f32 -> bf16 MFMA-B fragments) + permuted f32 gamma/beta.
// (unchanged from R15)
// ---------------------------------------------------------------------------
__global__ __launch_bounds__(256) void repack_w(const float* __restrict__ W1,
                                                const float* __restrict__ W2,
                                                const float* __restrict__ gamma,
                                                const float* __restrict__ beta,
                                                unsigned short* __restrict__ wp1,
                                                unsigned short* __restrict__ wp2,
                                                float* __restrict__ gbt) {
  int t = blockIdx.x * 256 + threadIdx.x;
  int lane = t & 63, g = t >> 6;
  if (g < 96) {                                   // W1: 3*8*4 groups
    int layer = g >> 5, rem = g & 31, nt = rem >> 2, ks = rem & 3;
    int n = nt * 16 + (lane & 15);
    int kb = ks * 32 + (lane >> 4) * 8;
    ushort8 v;
#pragma unroll
    for (int r = 0; r < 8; ++r) {
      int k = kb + r;
      int srck = (layer == 0) ? k : pi2(k);
      union { __bf16 b; unsigned short u; } c;
      c.b = (__bf16)W1[(layer * 128 + srck) * 128 + n];
      v[r] = c.u;
    }
    *reinterpret_cast<ushort8*>(wp1 + ((size_t)g * 64 + lane) * 8) = v;
  } else if (g < 144) {                           // W2: 3*4*4 groups, k by p2l
    int g2 = g - 96;
    int layer = g2 >> 4, rem = g2 & 15, nt = rem >> 2, ks = rem & 3;
    int n = nt * 16 + (lane & 15);
    int kb = ks * 32 + (lane >> 4) * 8;
    ushort8 v;
#pragma unroll
    for (int r = 0; r < 8; ++r) {
      union { __bf16 b; unsigned short u; } c;
      c.b = (__bf16)W2[(layer * 128 + p2l(kb + r)) * 64 + n];
      v[r] = c.u;
    }
    *reinterpret_cast<ushort8*>(wp2 + ((size_t)g2 * 64 + lane) * 8) = v;
  } else if (g < 150) {                           // gamma/beta f32, padded
    int g2 = g - 144;                             // 0..5
    int layer = g2 >> 1, param = g2 & 1;
    const float* src = (param == 0 ? gamma : beta) + layer * 128;
    float* dst = gbt + layer * 288 + param * 144;
    int p0 = lane * 2;
#pragma unroll
    for (int u = 0; u < 2; ++u) {
      int p = p0 + u;
      dst[(p >> 5) * 36 + (p & 31)] = src[p2l(p)];
    }
  }
}

// ---------------------------------------------------------------------------
// Fused depth-3 MLP stack: TWO batch rows per 4-wave block, software-pipelined
// with a ONE-PHASE SKEW so every barrier interval mixes an LDS-heavy phase of
// one row with a VALU-heavy phase of the other (R5-R15 measured VALU-issue
// ~88us and LDS-pipe ~75us SERIALIZED at ~170us; mixing overlaps them).
//   phases/row/layer: G1 | writeH | LN(in-place) | G2+pool | packX
//   intervals: {A.G1,B.packX'} {A.wH,B.G1} {A.LN,B.wH} {A.G2,B.LN} {A.pk,B.G2}
// Each row has its own in-place 16KB buffer (R5-verified hazards), 4-bit
// swizzle byte^=((row&15)<<4), pi2/p2l phys layouts, bias-in-C-init, f32 gbuf.
// 2.5 barriers/row/layer (was 3). No min-waves bound (R4/R6: forcing spills).
// ---------------------------------------------------------------------------
__global__ __launch_bounds__(256) void fused_mlp(
    const float* __restrict__ hidden,
    const float* __restrict__ b1,
    const float* __restrict__ b2,
    const unsigned short* __restrict__ wp1u,
    const unsigned short* __restrict__ wp2u,
    const float* __restrict__ gbt,
    float* __restrict__ out) {
  __shared__ __align__(16) unsigned short xAu[NL * NH];    // 16384 B (row A)
  __shared__ __align__(16) unsigned short xBu[NL * NH];    // 16384 B (row B)
  __shared__ __align__(16) float gbuf[864];                // 3456 B

  const int tid = threadIdx.x;
  const int wave = tid >> 6, lane = tid & 63;
  const int ci = lane & 15, lg = lane >> 4;
  char* xA = reinterpret_cast<char*>(xAu);
  char* xB = reinterpret_cast<char*>(xBu);

  const int abase = ci * 256;                 // fragment-read row base
  const int axor = ci << 4;                   // 4-bit row swizzle
  const int dby = (wave * 16 + ci) * 4;       // epilogue phys dword byte col

  // stage gamma/beta (f32, padded layout) into LDS
  if (tid < 96) {
#pragma unroll
    for (int u = 0; u < 9; ++u) gbuf[tid * 9 + u] = gbt[tid * 9 + u];
  }

  // ---- stage 0: load both rows (f32) -> xA/xB (bf16, swizzled) ----
  {
    const float* srcA = hidden + (size_t)(2 * blockIdx.x) * (NL * NH);
#pragma unroll
    for (int rr = 0; rr < 2; ++rr) {
      const float* src = srcA + rr * (NL * NH);
      char* xr = rr ? xB : xA;
#pragma unroll
      for (int i = 0; i < 4; ++i) {
        int f = i * 256 + tid;
        int row = f >> 4;
        int cb = (f & 15) * 16;
        const float4* p = reinterpret_cast<const float4*>(src + f * 8);
        float4 a = p[0], bq = p[1];
        bf16x8 v;
        v[0] = (__bf16)a.x;  v[1] = (__bf16)a.y;  v[2] = (__bf16)a.z;  v[3] = (__bf16)a.w;
        v[4] = (__bf16)bq.x; v[5] = (__bf16)bq.y; v[6] = (__bf16)bq.z; v[7] = (__bf16)bq.w;
        *reinterpret_cast<bf16x8*>(xr + row * 256 + (cb ^ ((row & 15) << 4))) = v;
      }
    }
  }
  __syncthreads();

  // persistent per-row register state
  f32x4 accA[4][2], accB[4][2], acc2A[4], acc2B[4];
  float mmA = 0.f, mmB = 0.f;

  // ---- phase bodies (verbatim R15 code, parameterized by row buffer) ----
  auto G1 = [&](const char* xR, f32x4 (&acc)[4][2], int l) {
    const unsigned short* wl1 = wp1u + (size_t)l * 16384;
    float bv0 = b1[l * 128 + wave * 32 + ci];
    float bv1 = b1[l * 128 + wave * 32 + 16 + ci];
#pragma unroll
    for (int mt = 0; mt < 4; ++mt) {
      acc[mt][0] = f32x4{bv0, bv0, bv0, bv0};
      acc[mt][1] = f32x4{bv1, bv1, bv1, bv1};
    }
#pragma unroll
    for (int ks = 0; ks < 4; ++ks) {
      bf16x8 bf0 = *reinterpret_cast<const bf16x8*>(
          wl1 + (((wave * 2 + 0) * 4 + ks) * 64 + lane) * 8);
      bf16x8 bf1 = *reinterpret_cast<const bf16x8*>(
          wl1 + (((wave * 2 + 1) * 4 + ks) * 64 + lane) * 8);
      int cbx = ((ks * 64 + lg * 16) ^ axor) + abase;
#pragma unroll
      for (int mt = 0; mt < 4; ++mt) {
        bf16x8 af = *reinterpret_cast<const bf16x8*>(xR + mt * 4096 + cbx);
        acc[mt][0] = __builtin_amdgcn_mfma_f32_16x16x32_bf16(af, bf0, acc[mt][0], 0, 0, 0);
        acc[mt][1] = __builtin_amdgcn_mfma_f32_16x16x32_bf16(af, bf1, acc[mt][1], 0, 0, 0);
      }
    }
  };

  auto WH = [&](char* xR, f32x4 (&acc)[4][2]) {
#pragma unroll
    for (int mt = 0; mt < 4; ++mt)
#pragma unroll
      for (int r = 0; r < 4; ++r) {
        int row = mt * 16 + lg * 4 + r;
        *reinterpret_cast<unsigned*>(
            xR + row * 256 + (dby ^ ((lg * 4 + r) << 4))) =
            pk2(acc[mt][0][r], acc[mt][1][r]);
      }
  };

  auto LN = [&](char* xR, int l) {
    const int row = wave * 16 + (lane >> 2);
    const int q = lane & 3;
    const int rb = row * 256, rx = (lane >> 2) << 4;
    bf16x8 h0 = *reinterpret_cast<const bf16x8*>(xR + rb + ((q * 64 + 0) ^ rx));
    bf16x8 h1 = *reinterpret_cast<const bf16x8*>(xR + rb + ((q * 64 + 16) ^ rx));
    bf16x8 h2 = *reinterpret_cast<const bf16x8*>(xR + rb + ((q * 64 + 32) ^ rx));
    bf16x8 h3 = *reinterpret_cast<const bf16x8*>(xR + rb + ((q * 64 + 48) ^ rx));
    f32x2 f[16];
#pragma unroll
    for (int cch = 0; cch < 4; ++cch) {
      bf16x8 hv = (cch == 0) ? h0 : (cch == 1) ? h1 : (cch == 2) ? h2 : h3;
#pragma unroll
      for (int j2 = 0; j2 < 4; ++j2)
        f[cch * 4 + j2] = f32x2{(float)hv[j2 * 2], (float)hv[j2 * 2 + 1]};
    }
    f32x2 s2 = {0.f, 0.f}, q2 = {0.f, 0.f};
#pragma unroll
    for (int i = 0; i < 16; ++i) { s2 += f[i]; q2 += f[i] * f[i]; }
    float s = s2.x + s2.y, sq = q2.x + q2.y;
    s += __shfl_xor(s, 1);  sq += __shfl_xor(sq, 1);
    s += __shfl_xor(s, 2);  sq += __shfl_xor(sq, 2);
    float mu = s * (1.f / 128.f);
    float var = sq * (1.f / 128.f) - mu * mu;
    float rs = rsqrtf(var + 1e-5f);
    const f32x2* gl = reinterpret_cast<const f32x2*>(gbuf + l * 288 + q * 36);
    const f32x2* bl = reinterpret_cast<const f32x2*>(gbuf + l * 288 + 144 + q * 36);
#pragma unroll
    for (int cch = 0; cch < 4; ++cch) {
      union { unsigned u[4]; bf16x8 v; } yy;
#pragma unroll
      for (int j2 = 0; j2 < 4; ++j2) {
        int i = cch * 4 + j2;
        f32x2 a2 = gl[i] * rs;
        f32x2 c2 = bl[i] - a2 * mu;
        f32x2 y2 = f[i] * a2 + c2;
        yy.u[j2] = pk2(fmaxf(y2.x, 0.f), fmaxf(y2.y, 0.f));
      }
      *reinterpret_cast<bf16x8*>(xR + rb + ((q * 64 + cch * 16) ^ rx)) = yy.v;
    }
  };

  auto G2 = [&](const char* xR, f32x4 (&a2)[4], float& mm, int l) {
    const unsigned short* wl2 = wp2u + (size_t)l * 8192;
    float b2v = b2[l * 64 + wave * 16 + ci];
#pragma unroll
    for (int mt = 0; mt < 4; ++mt) a2[mt] = f32x4{b2v, b2v, b2v, b2v};
#pragma unroll
    for (int ks = 0; ks < 4; ++ks) {
      bf16x8 bfr = *reinterpret_cast<const bf16x8*>(
          wl2 + ((wave * 4 + ks) * 64 + lane) * 8);
      int cbx = ((ks * 64 + lg * 16) ^ axor) + abase;
#pragma unroll
      for (int mt = 0; mt < 4; ++mt) {
        bf16x8 af = *reinterpret_cast<const bf16x8*>(xR + mt * 4096 + cbx);
        a2[mt] = __builtin_amdgcn_mfma_f32_16x16x32_bf16(af, bfr, a2[mt], 0, 0, 0);
      }
    }
    float m = -3.0e38f;
#pragma unroll
    for (int mt = 0; mt < 4; ++mt)
#pragma unroll
      for (int r = 0; r < 4; ++r) m = fmaxf(m, a2[mt][r]);
    m = fmaxf(m, __shfl_xor(m, 16));
    m = fmaxf(m, __shfl_xor(m, 32));
    mm = m;
  };

  auto PK = [&](char* xR, f32x4 (&a2)[4], float mm) {
#pragma unroll
    for (int mt = 0; mt < 4; ++mt)
#pragma unroll
      for (int r = 0; r < 4; ++r) {
        int row = mt * 16 + lg * 4 + r;
        *reinterpret_cast<unsigned*>(
            xR + row * 256 + (dby ^ ((lg * 4 + r) << 4))) =
            pk2(a2[mt][r], mm);
      }
  };

  auto OUTW = [&](int rsel, float mm) {
    if (lg == 0) {
      size_t o = (size_t)(2 * blockIdx.x + rsel) * 128 + wave * 16 + ci;
      out[o] = mm;
      out[o + 64] = mm;
    }
  };

  // ---- skewed 2-row pipeline: B one phase behind A ----
  for (int l = 0; l < 3; ++l) {
    G1(xA, accA, l);
    if (l) PK(xB, acc2B, mmB);         // B.packX of layer l-1 (l-1 <= 1)
    __syncthreads();
    WH(xA, accA);
    G1(xB, accB, l);
    __syncthreads();
    LN(xA, l);
    WH(xB, accB);
    __syncthreads();
    G2(xA, acc2A, mmA, l);
    LN(xB, l);
    __syncthreads();
    if (l < 2) PK(xA, acc2A, mmA); else OUTW(0, mmA);
    G2(xB, acc2B, mmB, l);
    __syncthreads();
  }
  OUTW(1, mmB);
}

extern "C" void kernel_launch(void* const* d_in, const int* in_sizes, int n_in,
                              void* d_out, int out_size, void* d_ws, size_t ws_size,
                              hipStream_t stream) {
  const float* hidden = (const float*)d_in[0];
  const float* W1 = (const float*)d_in[1];
  const float* b1 = (const float*)d_in[2];
  const float* gamma = (const float*)d_in[3];
  const float* beta = (const float*)d_in[4];
  const float* W2 = (const float*)d_in[5];
  const float* b2 = (const float*)d_in[6];
  (void)in_sizes; (void)n_in; (void)out_size; (void)ws_size;

  unsigned short* wp1 = (unsigned short*)d_ws;          // 49152 ushorts
  unsigned short* wp2 = wp1 + 3 * 8 * 4 * 64 * 8;       // 24576 ushorts
  float* gbt = (float*)(wp2 + 3 * 4 * 4 * 64 * 8);      // 864 f32 (padded)
  float* out = (float*)d_out;

  repack_w<<<38, 256, 0, stream>>>(W1, W2, gamma, beta, wp1, wp2, gbt);
  fused_mlp<<<NB / 2, 256, 0, stream>>>(hidden, b1, b2, wp1, wp2, gbt, out);
}